// Round 1
// baseline (145.740 us; speedup 1.0000x reference)
//
#include <hip/hip_runtime.h>
#include <math.h>

namespace {
constexpr int kH = 512;
constexpr int kN = 64;
constexpr int kL = 4096;
constexpr int kM = 2048;    // L/2
constexpr int kLf = 2049;   // L/2 + 1
constexpr int kThreads = 256;
constexpr float kPi = 3.14159265358979323846f;
}

// One block per head h.
// Phase 0: stage per-(h,n) constants into LDS, build twiddle table.
// Phase 1: spectrum k_f[l] for l=0..2048 into LDS (X).
//   Using u = (1+omega)/2:  1/(z - A) = u / (2 - u*(2+A)),  and since
//   r_ab = u*s_ab and the final scale is 1/u:
//     k_f = s00 - u*s01*s10 / (1 + u*s11)      (well-conditioned at Nyquist)
// Phase 2: irfft length 4096 via packed-real trick: build Z[k] (k=0..2047)
//   from X, inverse complex DFT of size 2048 (bit-reversed DIT, e^{+i} twiddles,
//   1/M normalization at the store), unpack x[2n]=Re z[n], x[2n+1]=Im z[n].
__global__ __launch_bounds__(kThreads)
void s4_fused(const float* __restrict__ A_real,
              const float* __restrict__ A_imag,
              const float* __restrict__ Bv,
              const float* __restrict__ Cv,
              const float* __restrict__ Pv,
              const float* __restrict__ inv_dt,
              float* __restrict__ out)
{
    __shared__ float  hn[kN * 12];     // per-n: 2+ar, ai, v00r,i, v01r,i, v10r,i, v11r,i, pad
    __shared__ float2 X[kLf];          // spectrum k_f
    __shared__ float2 W2[kM];          // FFT work buffer
    __shared__ float2 TW[kM / 2];      // twiddles e^{+2pi i j / 2048}

    const int h   = blockIdx.x;
    const int tid = threadIdx.x;

    // ---------------- phase 0: stage constants ----------------
    if (tid < kN) {
        const int n = tid;
        const int idx = h * kN + n;
        const float dt = expf(inv_dt[h]);
        const float ar = -expf(A_real[idx]) * dt;   // Re(A*dt)
        const float ai =  A_imag[idx] * dt;         // Im(A*dt)
        const float br = Bv[idx*2+0], bi = Bv[idx*2+1];
        const float cr = Cv[idx*2+0], ci = Cv[idx*2+1];
        const float pr = Pv[idx*2+0], pi = Pv[idx*2+1];
        float* row = &hn[n * 12];
        row[0]  = 2.0f + ar;
        row[1]  = ai;
        row[2]  = (br*cr - bi*ci) * dt;   // v00 = B*C*dt
        row[3]  = (br*ci + bi*cr) * dt;
        row[4]  = (br*pr + bi*pi) * dt;   // v01 = B*conj(P)*dt
        row[5]  = (bi*pr - br*pi) * dt;
        row[6]  = (pr*cr - pi*ci) * dt;   // v10 = P*C*dt
        row[7]  = (pr*ci + pi*cr) * dt;
        row[8]  = (pr*pr + pi*pi) * dt;   // v11 = |P|^2*dt (real)
        row[9]  = 0.0f;
        row[10] = 0.0f;
        row[11] = 0.0f;
    }
    for (int j = tid; j < kM / 2; j += kThreads) {
        float s, c;
        sincosf((2.0f * kPi / (float)kM) * (float)j, &s, &c);
        TW[j] = make_float2(c, s);       // e^{+2pi i j / 2048}
    }
    __syncthreads();

    // ---------------- phase 1: spectrum ----------------
    for (int l = tid; l < kLf; l += kThreads) {
        float s, c;
        sincosf((2.0f * kPi / (float)kL) * (float)l, &s, &c);
        const float ur = 0.5f * (1.0f + c);   // u = (1+omega)/2, omega = e^{-i th}
        const float ui = -0.5f * s;

        float s00r = 0.f, s00i = 0.f, s01r = 0.f, s01i = 0.f;
        float s10r = 0.f, s10i = 0.f, s11r = 0.f, s11i = 0.f;

        #pragma unroll 8
        for (int n = 0; n < kN; ++n) {
            const float* row = &hn[n * 12];
            const float tr  = row[0];   // 2 + ar
            const float ai  = row[1];
            const float v00r = row[2], v00i = row[3];
            const float v01r = row[4], v01i = row[5];
            const float v10r = row[6], v10i = row[7];
            const float v11r = row[8];

            const float p1 = ur * tr;
            const float p2 = ui * ai;
            const float p3 = ur * ai;
            const float p4 = ui * tr;
            // den1 = 2 - u*(tr, ai),  den2 = 2 - u*(tr, -ai)
            const float a_  = 2.0f - p1;
            const float d1r = a_ + p2;
            const float d1i = -(p3 + p4);
            const float d2r = a_ - p2;
            const float d2i = p3 - p4;

            const float q1 = __builtin_amdgcn_rcpf(d1r*d1r + d1i*d1i);
            const float q2 = __builtin_amdgcn_rcpf(d2r*d2r + d2i*d2i);
            const float e1r = d1r * q1, e1i = -d1i * q1;   // 1/den1
            const float e2r = d2r * q2, e2i = -d2i * q2;   // 1/den2

            // s += v*e1 + conj(v)*e2
            //   re: vr*(e1r+e2r) + vi*(e2i - e1i)
            //   im: vr*(e1i+e2i) + vi*(e1r - e2r)
            const float fr = e1r + e2r;
            const float fi = e1i + e2i;
            const float gr = e2i - e1i;
            const float gi = e1r - e2r;

            s00r += v00r * fr + v00i * gr;  s00i += v00r * fi + v00i * gi;
            s01r += v01r * fr + v01i * gr;  s01i += v01r * fi + v01i * gi;
            s10r += v10r * fr + v10i * gr;  s10i += v10r * fi + v10i * gi;
            s11r += v11r * fr;              s11i += v11r * fi;   // v11 real
        }

        // kf = s00 - u*s01*s10 / (1 + u*s11)
        const float nr = s01r * s10r - s01i * s10i;
        const float ni = s01r * s10i + s01i * s10r;
        const float tr2 = ur * nr - ui * ni;
        const float ti2 = ur * ni + ui * nr;
        const float dr2 = 1.0f + ur * s11r - ui * s11i;
        const float di2 = ur * s11i + ui * s11r;
        const float q   = __builtin_amdgcn_rcpf(dr2*dr2 + di2*di2);
        const float kr  = s00r - (tr2 * dr2 + ti2 * di2) * q;
        const float ki  = s00i - (ti2 * dr2 - tr2 * di2) * q;
        X[l] = make_float2(kr, ki);
    }
    __syncthreads();

    // ---------------- phase 2: build Z (bit-reversed) ----------------
    // E = (X[k] + conj(X[M-k]))/2 ; O = e^{+2pi i k/L} * (X[k] - conj(X[M-k]))/2
    // Z[k]   = (Er - Oi, Ei + Or)
    // Z[M-k] = (Er + Oi, Or - Ei)   (k != 0, M/2)
    for (int k = tid; k <= kM / 2; k += kThreads) {
        const float2 Xa = X[k];
        const float2 Xb = X[kM - k];
        const float Er = 0.5f * (Xa.x + Xb.x);
        const float Ei = 0.5f * (Xa.y - Xb.y);
        const float Dr = 0.5f * (Xa.x - Xb.x);
        const float Di = 0.5f * (Xa.y + Xb.y);
        float s, c;
        sincosf((2.0f * kPi / (float)kL) * (float)k, &s, &c);
        const float Or = c * Dr - s * Di;
        const float Oi = c * Di + s * Dr;
        const int rk = (int)(__brev((unsigned)k) >> 21);          // 11-bit reversal
        W2[rk] = make_float2(Er - Oi, Ei + Or);
        if (k != 0 && k != kM / 2) {
            const int rmk = (int)(__brev((unsigned)(kM - k)) >> 21);
            W2[rmk] = make_float2(Er + Oi, Or - Ei);
        }
    }
    __syncthreads();

    // ---------------- phase 2b: inverse DFT, size 2048, DIT ----------------
    for (int hs = 1; hs < kM; hs <<= 1) {
        const int tw_stride = (kM / 2) / hs;
        for (int j = tid; j < kM / 2; j += kThreads) {
            const int pos = j & (hs - 1);
            const int grp = j / hs;
            const int i0  = grp * 2 * hs + pos;
            const int i1  = i0 + hs;
            const float2 tw = TW[pos * tw_stride];
            const float2 a = W2[i0];
            const float2 b = W2[i1];
            const float tr = tw.x * b.x - tw.y * b.y;
            const float ti = tw.x * b.y + tw.y * b.x;
            W2[i0] = make_float2(a.x + tr, a.y + ti);
            W2[i1] = make_float2(a.x - tr, a.y - ti);
        }
        __syncthreads();
    }

    // ---------------- phase 3: unpack + store ----------------
    const float invM = 1.0f / (float)kM;
    float2* out2 = (float2*)(out + (size_t)h * kL);
    for (int n = tid; n < kM; n += kThreads) {
        const float2 zn = W2[n];
        out2[n] = make_float2(zn.x * invM, zn.y * invM);
    }
}

extern "C" void kernel_launch(void* const* d_in, const int* in_sizes, int n_in,
                              void* d_out, int out_size, void* d_ws, size_t ws_size,
                              hipStream_t stream) {
    const float* A_real = (const float*)d_in[0];
    const float* A_imag = (const float*)d_in[1];
    const float* B      = (const float*)d_in[2];
    const float* C      = (const float*)d_in[3];
    const float* P      = (const float*)d_in[4];
    const float* inv_dt = (const float*)d_in[5];
    // d_in[6] is L == 4096 (compile-time constant here)
    float* out = (float*)d_out;

    s4_fused<<<dim3(kH), dim3(kThreads), 0, stream>>>(
        A_real, A_imag, B, C, P, inv_dt, out);
}

// Round 2
// 138.824 us; speedup vs baseline: 1.0498x; 1.0498x over previous
//
#include <hip/hip_runtime.h>
#include <math.h>

namespace {
constexpr int kH = 512;
constexpr int kN = 64;
constexpr int kL = 4096;
constexpr int kM = 2048;    // L/2
constexpr int kLf = 2049;   // L/2 + 1
constexpr int kThreads = 256;
constexpr float kPi = 3.14159265358979323846f;
}

// ===================== Kernel 1: spectrum =====================
// grid = 512 heads x 4 slices. Each block computes 512 bins of k_f for its
// head (2 bins/thread), writing X[l] (l=0..2047) as float2 into d_out's
// region for that head (2048 float2 == 4096 float == one head's out slice).
// Nyquist bin (l=2048) is handled in kernel 2 via the closed form u=0:
//   k_f[2048] = sum_n B*C*dt.
//
// Math (u = (1+omega)/2, 1/(z-A) = u/(2-u(2+A)), r = u*s, final scale 1/u):
//   k_f = s00 - u*s01*s10/(1 + u*s11)
// Conjugate-pair trick: with d1 = 2-u*(T+ia), d2 = 2-u*(T-ia), T=2+Re(A dt):
//   d1*d2   = 4 - 4uT + u^2*(T^2+a^2)
//   d1+d2   = 4 - 2uT
//   d2-d1   = 2ia*u
//   E=e1+e2 = (d1+d2)/(d1 d2),  F=e1-e2 = (d2-d1)/(d1 d2)
//   s_ab += ( vr*Er - vi*Fi,  vr*Ei + vi*Fr )      [v11 is real]
__global__ __launch_bounds__(kThreads)
void s4_spectrum(const float* __restrict__ A_real,
                 const float* __restrict__ A_imag,
                 const float* __restrict__ Bv,
                 const float* __restrict__ Cv,
                 const float* __restrict__ Pv,
                 const float* __restrict__ inv_dt,
                 float2* __restrict__ Xg)
{
    __shared__ float4 rows[kN * 3];   // per n: {4T,2T,2a,m},{v00r,i,v01r,i},{v10r,i,v11r,0}

    const int h     = blockIdx.x >> 2;
    const int slice = blockIdx.x & 3;
    const int tid   = threadIdx.x;

    if (tid < kN) {
        const int n   = tid;
        const int idx = h * kN + n;
        const float dt = expf(inv_dt[h]);
        const float ar = -expf(A_real[idx]) * dt;
        const float ai =  A_imag[idx] * dt;
        const float br = Bv[idx*2+0], bi = Bv[idx*2+1];
        const float cr = Cv[idx*2+0], ci = Cv[idx*2+1];
        const float pr = Pv[idx*2+0], pi = Pv[idx*2+1];
        const float T  = 2.0f + ar;
        const float m  = T*T + ai*ai;
        rows[n*3+0] = make_float4(4.0f*T, 2.0f*T, 2.0f*ai, m);
        rows[n*3+1] = make_float4((br*cr - bi*ci)*dt, (br*ci + bi*cr)*dt,
                                  (br*pr + bi*pi)*dt, (bi*pr - br*pi)*dt);
        rows[n*3+2] = make_float4((pr*cr - pi*ci)*dt, (pr*ci + pi*cr)*dt,
                                  (pr*pr + pi*pi)*dt, 0.0f);
    }
    __syncthreads();

    const int l0 = slice * 512 + tid;   // bins l0 and l0+256
    float s, c;
    sincosf((2.0f*kPi/(float)kL) * (float)l0, &s, &c);
    const float ur0 = 0.5f*(1.0f + c), ui0 = -0.5f*s;
    sincosf((2.0f*kPi/(float)kL) * (float)(l0 + 256), &s, &c);
    const float ur1 = 0.5f*(1.0f + c), ui1 = -0.5f*s;
    const float u2r0 = ur0*ur0 - ui0*ui0, u2i0 = 2.0f*ur0*ui0;
    const float u2r1 = ur1*ur1 - ui1*ui1, u2i1 = 2.0f*ur1*ui1;

    float a00r=0.f,a00i=0.f,a01r=0.f,a01i=0.f,a10r=0.f,a10i=0.f,a11r=0.f,a11i=0.f;
    float b00r=0.f,b00i=0.f,b01r=0.f,b01i=0.f,b10r=0.f,b10i=0.f,b11r=0.f,b11i=0.f;

    #pragma unroll 4
    for (int n = 0; n < kN; ++n) {
        const float4 r0 = rows[n*3+0];
        const float4 r1 = rows[n*3+1];
        const float4 r2 = rows[n*3+2];
        const float fourT = r0.x, twoT = r0.y, twoA = r0.z, m = r0.w;
        const float v00r = r1.x, v00i = r1.y, v01r = r1.z, v01i = r1.w;
        const float v10r = r2.x, v10i = r2.y, v11r = r2.z;

        // ---- bin 0 ----
        {
            const float t0  = fmaf(-fourT, ur0, 4.0f);
            const float pdr = fmaf(m, u2r0, t0);
            const float pdi = fmaf(m, u2i0, -fourT*ui0);
            const float Sr  = fmaf(-twoT, ur0, 4.0f);
            const float Si  = -twoT*ui0;
            const float Dr  = -twoA*ui0;
            const float Di  =  twoA*ur0;
            const float q   = __builtin_amdgcn_rcpf(fmaf(pdi, pdi, pdr*pdr));
            const float ipr = pdr*q, ipi = -pdi*q;
            const float Er  = Sr*ipr - Si*ipi;
            const float Ei  = Sr*ipi + Si*ipr;
            const float Fr  = Dr*ipr - Di*ipi;
            const float Fi  = Dr*ipi + Di*ipr;
            a00r = fmaf(v00r, Er, fmaf(-v00i, Fi, a00r));
            a00i = fmaf(v00r, Ei, fmaf( v00i, Fr, a00i));
            a01r = fmaf(v01r, Er, fmaf(-v01i, Fi, a01r));
            a01i = fmaf(v01r, Ei, fmaf( v01i, Fr, a01i));
            a10r = fmaf(v10r, Er, fmaf(-v10i, Fi, a10r));
            a10i = fmaf(v10r, Ei, fmaf( v10i, Fr, a10i));
            a11r = fmaf(v11r, Er, a11r);
            a11i = fmaf(v11r, Ei, a11i);
        }
        // ---- bin 1 ----
        {
            const float t0  = fmaf(-fourT, ur1, 4.0f);
            const float pdr = fmaf(m, u2r1, t0);
            const float pdi = fmaf(m, u2i1, -fourT*ui1);
            const float Sr  = fmaf(-twoT, ur1, 4.0f);
            const float Si  = -twoT*ui1;
            const float Dr  = -twoA*ui1;
            const float Di  =  twoA*ur1;
            const float q   = __builtin_amdgcn_rcpf(fmaf(pdi, pdi, pdr*pdr));
            const float ipr = pdr*q, ipi = -pdi*q;
            const float Er  = Sr*ipr - Si*ipi;
            const float Ei  = Sr*ipi + Si*ipr;
            const float Fr  = Dr*ipr - Di*ipi;
            const float Fi  = Dr*ipi + Di*ipr;
            b00r = fmaf(v00r, Er, fmaf(-v00i, Fi, b00r));
            b00i = fmaf(v00r, Ei, fmaf( v00i, Fr, b00i));
            b01r = fmaf(v01r, Er, fmaf(-v01i, Fi, b01r));
            b01i = fmaf(v01r, Ei, fmaf( v01i, Fr, b01i));
            b10r = fmaf(v10r, Er, fmaf(-v10i, Fi, b10r));
            b10i = fmaf(v10r, Ei, fmaf( v10i, Fr, b10i));
            b11r = fmaf(v11r, Er, b11r);
            b11i = fmaf(v11r, Ei, b11i);
        }
    }

    // tail: kf = s00 - u*s01*s10/(1+u*s11)
    {
        const float nr  = a01r*a10r - a01i*a10i;
        const float ni  = a01r*a10i + a01i*a10r;
        const float tr2 = ur0*nr - ui0*ni;
        const float ti2 = ur0*ni + ui0*nr;
        const float dr2 = 1.0f + ur0*a11r - ui0*a11i;
        const float di2 = ur0*a11i + ui0*a11r;
        const float q   = __builtin_amdgcn_rcpf(dr2*dr2 + di2*di2);
        Xg[h*kM + l0] = make_float2(a00r - (tr2*dr2 + ti2*di2)*q,
                                    a00i - (ti2*dr2 - tr2*di2)*q);
    }
    {
        const float nr  = b01r*b10r - b01i*b10i;
        const float ni  = b01r*b10i + b01i*b10r;
        const float tr2 = ur1*nr - ui1*ni;
        const float ti2 = ur1*ni + ui1*nr;
        const float dr2 = 1.0f + ur1*b11r - ui1*b11i;
        const float di2 = ur1*b11i + ui1*b11r;
        const float q   = __builtin_amdgcn_rcpf(dr2*dr2 + di2*di2);
        Xg[h*kM + l0 + 256] = make_float2(b00r - (tr2*dr2 + ti2*di2)*q,
                                          b00i - (ti2*dr2 - tr2*di2)*q);
    }
}

// ===================== Kernel 2: irfft =====================
// One block per head. Reads X[0..2047] from d_out (written by kernel 1),
// recomputes Nyquist X[2048] = sum_n B*C*dt, does packed-real 2048-pt
// inverse complex DFT in LDS, stores the 4096 real samples back over the
// same head's d_out region (reads are LDS-buffered before any store).
__global__ __launch_bounds__(kThreads)
void s4_ifft(const float* __restrict__ Bv,
             const float* __restrict__ Cv,
             const float* __restrict__ inv_dt,
             float* __restrict__ out)
{
    __shared__ float2 Xs[kLf];
    __shared__ float2 W2[kM];
    __shared__ float2 TW[kM / 2];

    const int h   = blockIdx.x;
    const int tid = threadIdx.x;
    const float2* Xg = (const float2*)(out + (size_t)h * kL);

    for (int k = tid; k < kM; k += kThreads) Xs[k] = Xg[k];

    if (tid < kN) {   // wave 0: Nyquist bin closed form
        const int idx = h * kN + tid;
        const float dt = expf(inv_dt[h]);
        const float br = Bv[idx*2+0], bi = Bv[idx*2+1];
        const float cr = Cv[idx*2+0], ci = Cv[idx*2+1];
        float vr = (br*cr - bi*ci) * dt;
        float vi = (br*ci + bi*cr) * dt;
        #pragma unroll
        for (int off = 32; off > 0; off >>= 1) {
            vr += __shfl_down(vr, off, 64);
            vi += __shfl_down(vi, off, 64);
        }
        if (tid == 0) Xs[kM] = make_float2(vr, vi);
    }
    for (int j = tid; j < kM / 2; j += kThreads) {
        float s, c;
        sincosf((2.0f * kPi / (float)kM) * (float)j, &s, &c);
        TW[j] = make_float2(c, s);       // e^{+2pi i j / 2048}
    }
    __syncthreads();

    // build Z (bit-reversed):
    // E = (X[k]+conj(X[M-k]))/2 ; O = e^{+2pi i k/L}*(X[k]-conj(X[M-k]))/2
    // Z[k] = (Er-Oi, Ei+Or); Z[M-k] = (Er+Oi, Or-Ei)
    for (int k = tid; k <= kM / 2; k += kThreads) {
        const float2 Xa = Xs[k];
        const float2 Xb = Xs[kM - k];
        const float Er = 0.5f * (Xa.x + Xb.x);
        const float Ei = 0.5f * (Xa.y - Xb.y);
        const float Dr = 0.5f * (Xa.x - Xb.x);
        const float Di = 0.5f * (Xa.y + Xb.y);
        float s, c;
        sincosf((2.0f * kPi / (float)kL) * (float)k, &s, &c);
        const float Or = c * Dr - s * Di;
        const float Oi = c * Di + s * Dr;
        const int rk = (int)(__brev((unsigned)k) >> 21);          // 11-bit reversal
        W2[rk] = make_float2(Er - Oi, Ei + Or);
        if (k != 0 && k != kM / 2) {
            const int rmk = (int)(__brev((unsigned)(kM - k)) >> 21);
            W2[rmk] = make_float2(Er + Oi, Or - Ei);
        }
    }
    __syncthreads();

    for (int hs = 1; hs < kM; hs <<= 1) {
        const int tw_stride = (kM / 2) / hs;
        for (int j = tid; j < kM / 2; j += kThreads) {
            const int pos = j & (hs - 1);
            const int grp = j / hs;
            const int i0  = grp * 2 * hs + pos;
            const int i1  = i0 + hs;
            const float2 tw = TW[pos * tw_stride];
            const float2 a = W2[i0];
            const float2 b = W2[i1];
            const float tr = tw.x * b.x - tw.y * b.y;
            const float ti = tw.x * b.y + tw.y * b.x;
            W2[i0] = make_float2(a.x + tr, a.y + ti);
            W2[i1] = make_float2(a.x - tr, a.y - ti);
        }
        __syncthreads();
    }

    const float invM = 1.0f / (float)kM;
    float2* out2 = (float2*)(out + (size_t)h * kL);
    for (int n = tid; n < kM; n += kThreads) {
        const float2 zn = W2[n];
        out2[n] = make_float2(zn.x * invM, zn.y * invM);
    }
}

extern "C" void kernel_launch(void* const* d_in, const int* in_sizes, int n_in,
                              void* d_out, int out_size, void* d_ws, size_t ws_size,
                              hipStream_t stream) {
    const float* A_real = (const float*)d_in[0];
    const float* A_imag = (const float*)d_in[1];
    const float* B      = (const float*)d_in[2];
    const float* C      = (const float*)d_in[3];
    const float* P      = (const float*)d_in[4];
    const float* inv_dt = (const float*)d_in[5];
    float* out = (float*)d_out;

    s4_spectrum<<<dim3(kH * 4), dim3(kThreads), 0, stream>>>(
        A_real, A_imag, B, C, P, inv_dt, (float2*)out);
    s4_ifft<<<dim3(kH), dim3(kThreads), 0, stream>>>(B, C, inv_dt, out);
}

// Round 3
// 125.942 us; speedup vs baseline: 1.1572x; 1.1023x over previous
//
#include <hip/hip_runtime.h>
#include <math.h>

namespace {
constexpr int kH = 512;
constexpr int kN = 64;
constexpr int kL = 4096;
constexpr int kM = 2048;    // L/2
constexpr int kThreads = 256;
constexpr int kFftThreads = 512;
constexpr float kPi = 3.14159265358979323846f;
}

// ===================== Kernel 1: spectrum =====================
// grid = 512 heads x 2 slices, 256 threads; each thread computes 4 bins
// (l, l+256, l+512, l+768). Bins 0..2047 -> d_out (2048 float2 per head).
// Nyquist (l=2048) handled in kernel 2.
//
// Direct-z math: z = 2i*t, t = tan(pi*l/L); 1/u = 1 + i*t.
//   e1 = 1/(z - A*dt)     = 1/(-ar + i*(2t - ai)),  w1 = 2t - ai
//   e2 = 1/(z - conj(A*dt)) = 1/(-ar + i*(2t + ai)), w2 = 2t + ai
//   q1 = 1/(ar^2+w1^2), q2 = 1/(ar^2+w2^2)  (one rcp via q=rcp(m1*m2))
//   r_ab += v*e1 + conj(v)*e2:
//     re += (-vr*ar)*(q1+q2) + vi*(w1*q1 - w2*q2)
//     im += (-vr)*(w1*q1 + w2*q2) + (-vi*ar)*(q1-q2)
//   k_f = (r00 - r01*r10/(1+r11)) * (1 + i*t)
__global__ __launch_bounds__(kThreads)
void s4_spectrum(const float* __restrict__ A_real,
                 const float* __restrict__ A_imag,
                 const float* __restrict__ Bv,
                 const float* __restrict__ Cv,
                 const float* __restrict__ Pv,
                 const float* __restrict__ inv_dt,
                 float2* __restrict__ Xg)
{
    __shared__ float4 rows[kN * 4];
    // row0: {ai, ar^2, -v11r*ar, -v11r}
    // row1: {-v00r*ar, -v00r, v00i, -v00i*ar}
    // row2: {-v01r*ar, -v01r, v01i, -v01i*ar}
    // row3: {-v10r*ar, -v10r, v10i, -v10i*ar}

    const int h     = blockIdx.x >> 1;
    const int slice = blockIdx.x & 1;
    const int tid   = threadIdx.x;

    if (tid < kN) {
        const int n   = tid;
        const int idx = h * kN + n;
        const float dt = expf(inv_dt[h]);
        const float ar = -expf(A_real[idx]) * dt;   // Re(A*dt) (negative)
        const float ai =  A_imag[idx] * dt;         // Im(A*dt)
        const float br = Bv[idx*2+0], bi = Bv[idx*2+1];
        const float cr = Cv[idx*2+0], ci = Cv[idx*2+1];
        const float pr = Pv[idx*2+0], pi = Pv[idx*2+1];
        const float v00r = (br*cr - bi*ci)*dt, v00i = (br*ci + bi*cr)*dt;
        const float v01r = (br*pr + bi*pi)*dt, v01i = (bi*pr - br*pi)*dt;  // B*conj(P)
        const float v10r = (pr*cr - pi*ci)*dt, v10i = (pr*ci + pi*cr)*dt;  // P*C
        const float v11r = (pr*pr + pi*pi)*dt;                              // |P|^2 (real)
        rows[n*4+0] = make_float4(ai, ar*ar, -v11r*ar, -v11r);
        rows[n*4+1] = make_float4(-v00r*ar, -v00r, v00i, -v00i*ar);
        rows[n*4+2] = make_float4(-v01r*ar, -v01r, v01i, -v01i*ar);
        rows[n*4+3] = make_float4(-v10r*ar, -v10r, v10i, -v10i*ar);
    }
    __syncthreads();

    const int lbase = slice * 1024 + tid;
    float tt[4], t2[4];
    #pragma unroll
    for (int b = 0; b < 4; ++b) {
        const int l = lbase + 256 * b;
        float s, c;
        sincosf((float)l * (kPi / (float)kL), &s, &c);
        tt[b] = s / c;                 // tan(pi*l/L), finite for l<=2047
        t2[b] = 2.0f * tt[b];
    }

    float s00r[4] = {0,0,0,0}, s00i[4] = {0,0,0,0};
    float s01r[4] = {0,0,0,0}, s01i[4] = {0,0,0,0};
    float s10r[4] = {0,0,0,0}, s10i[4] = {0,0,0,0};
    float s11r[4] = {0,0,0,0}, s11i[4] = {0,0,0,0};

    #pragma unroll 2
    for (int n = 0; n < kN; ++n) {
        const float4 r0 = rows[n*4+0];
        const float4 r1 = rows[n*4+1];
        const float4 r2 = rows[n*4+2];
        const float4 r3 = rows[n*4+3];
        #pragma unroll
        for (int b = 0; b < 4; ++b) {
            const float w1 = t2[b] - r0.x;
            const float w2 = t2[b] + r0.x;
            const float m1 = fmaf(w1, w1, r0.y);
            const float m2 = fmaf(w2, w2, r0.y);
            const float qq = __builtin_amdgcn_rcpf(m1 * m2);
            const float q1 = m2 * qq;
            const float q2 = m1 * qq;
            const float Qp = q1 + q2;
            const float Qm = q1 - q2;
            const float R  = w1 * q1;
            const float S  = w2 * q2;
            const float Pp = R + S;
            const float Mm = R - S;
            s00r[b] = fmaf(r1.x, Qp, fmaf(r1.z, Mm, s00r[b]));
            s00i[b] = fmaf(r1.y, Pp, fmaf(r1.w, Qm, s00i[b]));
            s01r[b] = fmaf(r2.x, Qp, fmaf(r2.z, Mm, s01r[b]));
            s01i[b] = fmaf(r2.y, Pp, fmaf(r2.w, Qm, s01i[b]));
            s10r[b] = fmaf(r3.x, Qp, fmaf(r3.z, Mm, s10r[b]));
            s10i[b] = fmaf(r3.y, Pp, fmaf(r3.w, Qm, s10i[b]));
            s11r[b] = fmaf(r0.z, Qp, s11r[b]);
            s11i[b] = fmaf(r0.w, Pp, s11i[b]);
        }
    }

    #pragma unroll
    for (int b = 0; b < 4; ++b) {
        const int l = lbase + 256 * b;
        const float nr = s01r[b]*s10r[b] - s01i[b]*s10i[b];
        const float ni = s01r[b]*s10i[b] + s01i[b]*s10r[b];
        const float dr = 1.0f + s11r[b];
        const float di = s11i[b];
        const float q  = __builtin_amdgcn_rcpf(fmaf(dr, dr, di*di));
        const float wr = (nr*dr + ni*di) * q;
        const float wi = (ni*dr - nr*di) * q;
        const float gr = s00r[b] - wr;
        const float gi = s00i[b] - wi;
        // k_f = g * (1 + i*t)
        Xg[h*kM + l] = make_float2(fmaf(-gi, tt[b], gr), fmaf(gr, tt[b], gi));
    }
}

// ===================== Kernel 2: irfft =====================
// One block (512 threads) per head. Builds Z directly from global X
// (Nyquist recomputed: k_f[2048] = sum_n Re(B*C)*dt, real), 2048-pt inverse
// complex DFT in LDS (bit-reversed DIT), unpack packed-real, store.
__global__ __launch_bounds__(kFftThreads)
void s4_ifft(const float* __restrict__ Bv,
             const float* __restrict__ Cv,
             const float* __restrict__ inv_dt,
             float* __restrict__ out)
{
    __shared__ float2 W2[kM];
    __shared__ float2 TW[kM / 2];
    __shared__ float  XnyqR;

    const int h   = blockIdx.x;
    const int tid = threadIdx.x;
    const float2* Xg = (const float2*)(out + (size_t)h * kL);

    if (tid < kN) {   // wave 0: Nyquist bin = sum_n Re(B*C)*dt (real)
        const int idx = h * kN + tid;
        const float dt = expf(inv_dt[h]);
        const float br = Bv[idx*2+0], bi = Bv[idx*2+1];
        const float cr = Cv[idx*2+0], ci = Cv[idx*2+1];
        float vr = (br*cr - bi*ci) * dt;
        #pragma unroll
        for (int off = 32; off > 0; off >>= 1) vr += __shfl_down(vr, off, 64);
        if (tid == 0) XnyqR = vr;
    }
    for (int j = tid; j < kM / 2; j += kFftThreads) {
        float s, c;
        sincosf((2.0f * kPi / (float)kM) * (float)j, &s, &c);
        TW[j] = make_float2(c, s);       // e^{+2pi i j / 2048}
    }
    __syncthreads();

    // build Z (bit-reversed) from global X:
    // E = (X[k]+conj(X[M-k]))/2 ; O = e^{+2pi i k/L}*(X[k]-conj(X[M-k]))/2
    // Z[k] = (Er-Oi, Ei+Or); Z[M-k] = (Er+Oi, Or-Ei)
    for (int k = tid; k <= kM / 2; k += kFftThreads) {
        const float2 Xa = Xg[k];
        const float2 Xb = (k == 0) ? make_float2(XnyqR, 0.0f) : Xg[kM - k];
        const float Er = 0.5f * (Xa.x + Xb.x);
        const float Ei = 0.5f * (Xa.y - Xb.y);
        const float Dr = 0.5f * (Xa.x - Xb.x);
        const float Di = 0.5f * (Xa.y + Xb.y);
        float s, c;
        sincosf((2.0f * kPi / (float)kL) * (float)k, &s, &c);
        const float Or = c * Dr - s * Di;
        const float Oi = c * Di + s * Dr;
        const int rk = (int)(__brev((unsigned)k) >> 21);          // 11-bit reversal
        W2[rk] = make_float2(Er - Oi, Ei + Or);
        if (k != 0 && k != kM / 2) {
            const int rmk = (int)(__brev((unsigned)(kM - k)) >> 21);
            W2[rmk] = make_float2(Er + Oi, Or - Ei);
        }
    }
    __syncthreads();

    for (int hs = 1; hs < kM; hs <<= 1) {
        const int tw_stride = (kM / 2) / hs;
        for (int j = tid; j < kM / 2; j += kFftThreads) {
            const int pos = j & (hs - 1);
            const int grp = j / hs;
            const int i0  = grp * 2 * hs + pos;
            const int i1  = i0 + hs;
            const float2 tw = TW[pos * tw_stride];
            const float2 a = W2[i0];
            const float2 b = W2[i1];
            const float tr = tw.x * b.x - tw.y * b.y;
            const float ti = tw.x * b.y + tw.y * b.x;
            W2[i0] = make_float2(a.x + tr, a.y + ti);
            W2[i1] = make_float2(a.x - tr, a.y - ti);
        }
        __syncthreads();
    }

    const float invM = 1.0f / (float)kM;
    float2* out2 = (float2*)(out + (size_t)h * kL);
    for (int n = tid; n < kM; n += kFftThreads) {
        const float2 zn = W2[n];
        out2[n] = make_float2(zn.x * invM, zn.y * invM);
    }
}

extern "C" void kernel_launch(void* const* d_in, const int* in_sizes, int n_in,
                              void* d_out, int out_size, void* d_ws, size_t ws_size,
                              hipStream_t stream) {
    const float* A_real = (const float*)d_in[0];
    const float* A_imag = (const float*)d_in[1];
    const float* B      = (const float*)d_in[2];
    const float* C      = (const float*)d_in[3];
    const float* P      = (const float*)d_in[4];
    const float* inv_dt = (const float*)d_in[5];
    float* out = (float*)d_out;

    s4_spectrum<<<dim3(kH * 2), dim3(kThreads), 0, stream>>>(
        A_real, A_imag, B, C, P, inv_dt, (float2*)out);
    s4_ifft<<<dim3(kH), dim3(kFftThreads), 0, stream>>>(B, C, inv_dt, out);
}

// Round 4
// 122.107 us; speedup vs baseline: 1.1935x; 1.0314x over previous
//
#include <hip/hip_runtime.h>
#include <math.h>

namespace {
constexpr int kH = 512;
constexpr int kN = 64;
constexpr int kL = 4096;
constexpr int kM = 2048;    // L/2
constexpr int kRec = 20;    // floats per (h,n) coefficient record
constexpr int kThreads = 256;
constexpr int kFftThreads = 512;
constexpr float kPi = 3.14159265358979323846f;
}

__device__ __forceinline__ int lpad(int i) { return i + (i >> 4); }

// ===================== Kernel 0: prep =====================
// One 64-thread block per head. Computes per-(h,n) SGPR-friendly coefficient
// records into d_ws, plus the (real) Nyquist bin value per head.
// Record: [ai, ar2, {a0,a1,b0,b1} x {00,01,10,11}, pad, pad]
//   s_r(l) += (a0 + a1*s) / D          s = 4t^2, t = tan(pi*l/L)
//   s_i(l) += t*(b0 + b1*s) / D        D = m1*m2 (product form, see spectrum)
// Derivation (from R3's verified Qp/Qm/Pp/Mm identities):
//   a0 = -2*C1*(vr*ar + vi*ai)   a1 = 2*(vi*ai - vr*ar)
//   b0 = -4*vr*(ar^2-ai^2) - 8*vi*ar*ai   b1 = -4*vr      [C1 = ar^2+ai^2]
__global__ __launch_bounds__(64)
void s4_prep(const float* __restrict__ A_real, const float* __restrict__ A_imag,
             const float* __restrict__ Bv, const float* __restrict__ Cv,
             const float* __restrict__ Pv, const float* __restrict__ inv_dt,
             float* __restrict__ cst, float* __restrict__ xnyq)
{
    const int h = blockIdx.x;
    const int n = threadIdx.x;
    const int idx = h * kN + n;
    const float dt = expf(inv_dt[h]);
    const float ar = -expf(A_real[idx]) * dt;   // Re(A*dt) (negative)
    const float ai =  A_imag[idx] * dt;         // Im(A*dt)
    const float br = Bv[idx*2+0], bi = Bv[idx*2+1];
    const float cr = Cv[idx*2+0], ci = Cv[idx*2+1];
    const float pr = Pv[idx*2+0], pi = Pv[idx*2+1];
    const float v00r = (br*cr - bi*ci)*dt, v00i = (br*ci + bi*cr)*dt;  // B*C
    const float v01r = (br*pr + bi*pi)*dt, v01i = (bi*pr - br*pi)*dt;  // B*conj(P)
    const float v10r = (pr*cr - pi*ci)*dt, v10i = (pr*ci + pi*cr)*dt;  // P*C
    const float v11r = (pr*pr + pi*pi)*dt;                              // |P|^2 (real)
    const float ar2 = ar*ar;
    const float C1  = ar2 + ai*ai;
    const float dd  = ar2 - ai*ai;

    float* r = cst + idx * kRec;
    r[0]  = ai;  r[1] = ar2;
    r[2]  = -2.f*C1*(v00r*ar + v00i*ai);  r[3]  = 2.f*(v00i*ai - v00r*ar);
    r[4]  = -4.f*v00r*dd - 8.f*v00i*ar*ai; r[5]  = -4.f*v00r;
    r[6]  = -2.f*C1*(v01r*ar + v01i*ai);  r[7]  = 2.f*(v01i*ai - v01r*ar);
    r[8]  = -4.f*v01r*dd - 8.f*v01i*ar*ai; r[9]  = -4.f*v01r;
    r[10] = -2.f*C1*(v10r*ar + v10i*ai);  r[11] = 2.f*(v10i*ai - v10r*ar);
    r[12] = -4.f*v10r*dd - 8.f*v10i*ar*ai; r[13] = -4.f*v10r;
    r[14] = -2.f*C1*(v11r*ar);            r[15] = -2.f*v11r*ar;
    r[16] = -4.f*v11r*dd;                 r[17] = -4.f*v11r;
    r[18] = 0.f; r[19] = 0.f;

    // Nyquist (u=0): k_f[2048] = sum_n Re(B*C)*dt  (real)
    float s = v00r;
    #pragma unroll
    for (int off = 32; off > 0; off >>= 1) s += __shfl_down(s, off, 64);
    if (n == 0) xnyq[h] = s;
}

// ===================== Kernel 1: spectrum =====================
// grid = 512 heads x 4 quarters, 256 threads, 2 bins/thread.
// All per-n constants arrive via wave-uniform s_load (SGPRs); every
// accumulation FMA has exactly one SGPR operand. No LDS.
// Basis per (n,bin):  w1 = 2t-ai, w2 = 2t+ai, m = ar^2+w^2, D = m1*m2,
//   invD = rcp(D), sD = s*invD, tD = t*invD, stD = s*tD.
// Tail: k_f = (s00 - s01*s10/(1+s11)) * (1 + i*t).
__global__ __launch_bounds__(kThreads)
void s4_spectrum(const float* __restrict__ cst, float2* __restrict__ Xg)
{
    const int h   = blockIdx.x >> 2;
    const int q   = blockIdx.x & 3;
    const int tid = threadIdx.x;
    const int la  = q * 512 + tid;
    const int lb  = la + 256;

    float sn, cn;
    sincosf((float)la * (kPi / (float)kL), &sn, &cn);
    const float ta = sn / cn, t2a = 2.f * ta, sa = t2a * t2a;   // s = 4t^2
    sincosf((float)lb * (kPi / (float)kL), &sn, &cn);
    const float tb = sn / cn, t2b = 2.f * tb, sb = t2b * t2b;

    float A00r=0,A00i=0,A01r=0,A01i=0,A10r=0,A10i=0,A11r=0,A11i=0;
    float B00r=0,B00i=0,B01r=0,B01i=0,B10r=0,B10i=0,B11r=0,B11i=0;

    const float* rec = cst + (size_t)h * kN * kRec;
    #pragma unroll 2
    for (int n = 0; n < kN; ++n) {
        const float* r = rec + n * kRec;   // wave-uniform -> s_load
        const float ai = r[0], ar2 = r[1];
        const float c00a = r[2],  c00b = r[3],  c00c = r[4],  c00d = r[5];
        const float c01a = r[6],  c01b = r[7],  c01c = r[8],  c01d = r[9];
        const float c10a = r[10], c10b = r[11], c10c = r[12], c10d = r[13];
        const float c11a = r[14], c11b = r[15], c11c = r[16], c11d = r[17];
        {   // bin A
            const float w1 = t2a - ai, w2 = t2a + ai;
            const float m1 = fmaf(w1, w1, ar2), m2 = fmaf(w2, w2, ar2);
            const float invD = __builtin_amdgcn_rcpf(m1 * m2);
            const float sD = sa * invD, tD = ta * invD, stD = sa * tD;
            A00r = fmaf(c00a, invD, A00r); A00r = fmaf(c00b, sD,  A00r);
            A00i = fmaf(c00c, tD,   A00i); A00i = fmaf(c00d, stD, A00i);
            A01r = fmaf(c01a, invD, A01r); A01r = fmaf(c01b, sD,  A01r);
            A01i = fmaf(c01c, tD,   A01i); A01i = fmaf(c01d, stD, A01i);
            A10r = fmaf(c10a, invD, A10r); A10r = fmaf(c10b, sD,  A10r);
            A10i = fmaf(c10c, tD,   A10i); A10i = fmaf(c10d, stD, A10i);
            A11r = fmaf(c11a, invD, A11r); A11r = fmaf(c11b, sD,  A11r);
            A11i = fmaf(c11c, tD,   A11i); A11i = fmaf(c11d, stD, A11i);
        }
        {   // bin B
            const float w1 = t2b - ai, w2 = t2b + ai;
            const float m1 = fmaf(w1, w1, ar2), m2 = fmaf(w2, w2, ar2);
            const float invD = __builtin_amdgcn_rcpf(m1 * m2);
            const float sD = sb * invD, tD = tb * invD, stD = sb * tD;
            B00r = fmaf(c00a, invD, B00r); B00r = fmaf(c00b, sD,  B00r);
            B00i = fmaf(c00c, tD,   B00i); B00i = fmaf(c00d, stD, B00i);
            B01r = fmaf(c01a, invD, B01r); B01r = fmaf(c01b, sD,  B01r);
            B01i = fmaf(c01c, tD,   B01i); B01i = fmaf(c01d, stD, B01i);
            B10r = fmaf(c10a, invD, B10r); B10r = fmaf(c10b, sD,  B10r);
            B10i = fmaf(c10c, tD,   B10i); B10i = fmaf(c10d, stD, B10i);
            B11r = fmaf(c11a, invD, B11r); B11r = fmaf(c11b, sD,  B11r);
            B11i = fmaf(c11c, tD,   B11i); B11i = fmaf(c11d, stD, B11i);
        }
    }

    {   // tail A
        const float nr = A01r*A10r - A01i*A10i;
        const float ni = A01r*A10i + A01i*A10r;
        const float dr = 1.f + A11r, di = A11i;
        const float qd = __builtin_amdgcn_rcpf(fmaf(dr, dr, di*di));
        const float wr = (nr*dr + ni*di) * qd;
        const float wi = (ni*dr - nr*di) * qd;
        const float gr = A00r - wr, gi = A00i - wi;
        Xg[h*kM + la] = make_float2(fmaf(-gi, ta, gr), fmaf(gr, ta, gi));
    }
    {   // tail B
        const float nr = B01r*B10r - B01i*B10i;
        const float ni = B01r*B10i + B01i*B10r;
        const float dr = 1.f + B11r, di = B11i;
        const float qd = __builtin_amdgcn_rcpf(fmaf(dr, dr, di*di));
        const float wr = (nr*dr + ni*di) * qd;
        const float wi = (ni*dr - nr*di) * qd;
        const float gr = B00r - wr, gi = B00i - wi;
        Xg[h*kM + lb] = make_float2(fmaf(-gi, tb, gr), fmaf(gr, tb, gi));
    }
}

// ===================== Kernel 2: irfft =====================
// One 512-thread block per head. Packed-real 2048-pt inverse complex DFT in
// LDS with index padding i+(i>>4) to break power-of-2 bank aliasing (worst
// offender was TW reads at middle stages: stride-128B => 32-way conflicts).
__global__ __launch_bounds__(kFftThreads)
void s4_ifft(const float* __restrict__ xnyq, float* __restrict__ out)
{
    __shared__ float2 W2[kM + kM / 16];
    __shared__ float2 TW[kM / 2 + kM / 32];

    const int h   = blockIdx.x;
    const int tid = threadIdx.x;
    const float2* Xg = (const float2*)(out + (size_t)h * kL);
    const float nyqR = xnyq[h];

    for (int j = tid; j < kM / 2; j += kFftThreads) {
        float s, c;
        sincosf((2.0f * kPi / (float)kM) * (float)j, &s, &c);
        TW[lpad(j)] = make_float2(c, s);       // e^{+2pi i j / 2048}
    }

    // build Z (bit-reversed) from global X:
    // E = (X[k]+conj(X[M-k]))/2 ; O = e^{+2pi i k/L}*(X[k]-conj(X[M-k]))/2
    // Z[k] = (Er-Oi, Ei+Or); Z[M-k] = (Er+Oi, Or-Ei)
    for (int k = tid; k <= kM / 2; k += kFftThreads) {
        const float2 Xa = Xg[k];
        const float2 Xb = (k == 0) ? make_float2(nyqR, 0.0f) : Xg[kM - k];
        const float Er = 0.5f * (Xa.x + Xb.x);
        const float Ei = 0.5f * (Xa.y - Xb.y);
        const float Dr = 0.5f * (Xa.x - Xb.x);
        const float Di = 0.5f * (Xa.y + Xb.y);
        float s, c;
        sincosf((2.0f * kPi / (float)kL) * (float)k, &s, &c);
        const float Or = c * Dr - s * Di;
        const float Oi = c * Di + s * Dr;
        const int rk = (int)(__brev((unsigned)k) >> 21);          // 11-bit reversal
        W2[lpad(rk)] = make_float2(Er - Oi, Ei + Or);
        if (k != 0 && k != kM / 2) {
            const int rmk = (int)(__brev((unsigned)(kM - k)) >> 21);
            W2[lpad(rmk)] = make_float2(Er + Oi, Or - Ei);
        }
    }
    __syncthreads();

    for (int hs = 1; hs < kM; hs <<= 1) {
        const int tw_stride = (kM / 2) / hs;
        for (int j = tid; j < kM / 2; j += kFftThreads) {
            const int pos = j & (hs - 1);
            const int grp = j / hs;
            const int i0  = grp * 2 * hs + pos;
            const int i1  = i0 + hs;
            const float2 tw = TW[lpad(pos * tw_stride)];
            const float2 a = W2[lpad(i0)];
            const float2 b = W2[lpad(i1)];
            const float tr = tw.x * b.x - tw.y * b.y;
            const float ti = tw.x * b.y + tw.y * b.x;
            W2[lpad(i0)] = make_float2(a.x + tr, a.y + ti);
            W2[lpad(i1)] = make_float2(a.x - tr, a.y - ti);
        }
        __syncthreads();
    }

    const float invM = 1.0f / (float)kM;
    float2* out2 = (float2*)(out + (size_t)h * kL);
    for (int n = tid; n < kM; n += kFftThreads) {
        const float2 zn = W2[lpad(n)];
        out2[n] = make_float2(zn.x * invM, zn.y * invM);
    }
}

extern "C" void kernel_launch(void* const* d_in, const int* in_sizes, int n_in,
                              void* d_out, int out_size, void* d_ws, size_t ws_size,
                              hipStream_t stream) {
    const float* A_real = (const float*)d_in[0];
    const float* A_imag = (const float*)d_in[1];
    const float* B      = (const float*)d_in[2];
    const float* C      = (const float*)d_in[3];
    const float* P      = (const float*)d_in[4];
    const float* inv_dt = (const float*)d_in[5];
    float* out = (float*)d_out;

    float* cst  = (float*)d_ws;                       // 512*64*20 floats = 2.62 MB
    float* xnyq = cst + (size_t)kH * kN * kRec;       // +512 floats

    s4_prep<<<dim3(kH), dim3(64), 0, stream>>>(A_real, A_imag, B, C, P, inv_dt,
                                               cst, xnyq);
    s4_spectrum<<<dim3(kH * 4), dim3(kThreads), 0, stream>>>(cst, (float2*)out);
    s4_ifft<<<dim3(kH), dim3(kFftThreads), 0, stream>>>(xnyq, out);
}